// Round 5
// baseline (344.895 us; speedup 1.0000x reference)
//
#include <hip/hip_runtime.h>

#define D 128
#define NEG_SLOPE 0.2f

typedef __attribute__((ext_vector_type(8))) short short8;
typedef __attribute__((ext_vector_type(4))) float f32x4;

__device__ __forceinline__ float wred_sum(float v){
#pragma unroll
  for (int m = 32; m; m >>= 1) v += __shfl_xor(v, m);
  return v;
}
__device__ __forceinline__ int wred_sumi(int v){
#pragma unroll
  for (int m = 32; m; m >>= 1) v += __shfl_xor(v, m);
  return v;
}
__device__ __forceinline__ float wred_max(float v){
#pragma unroll
  for (int m = 32; m; m >>= 1) v = fmaxf(v, __shfl_xor(v, m));
  return v;
}
__device__ __forceinline__ unsigned short bf16r(float f){
  unsigned int u = __float_as_uint(f);
  u += 0x7fffu + ((u >> 16) & 1u);
  return (unsigned short)(u >> 16);
}
__device__ __forceinline__ float bf2f(unsigned int hi16){
  return __uint_as_float(hi16 << 16);
}

// K1: weight prep (bf16 transposes + we = W_edge@att_edge) + zero cnt
__global__ void k_prep0(const float* __restrict__ W_lin, const float* __restrict__ W1,
                        const float* __restrict__ W2, const float* __restrict__ W_edge,
                        const float* __restrict__ att_edge,
                        unsigned short* __restrict__ Wlt, unsigned short* __restrict__ W1t,
                        unsigned short* __restrict__ W2t, float* __restrict__ we,
                        int* __restrict__ cnt, int N){
  int t = blockIdx.x * blockDim.x + threadIdx.x;
  if (t < N) cnt[t] = 0;
  if (t < 128 * 128){
    int c = t >> 7, k = t & 127;
    Wlt[t] = bf16r(W_lin[k * 128 + c]);
  } else if (t < 128 * 128 + 512 * 128){
    int u = t - 128 * 128; int c = u >> 7, k = u & 127;
    W1t[u] = bf16r(W1[k * 512 + c]);
  } else if (t < 128 * 128 + 512 * 128 + 128 * 512){
    int u = t - (128 * 128 + 512 * 128); int c = u >> 9, k = u & 511;
    W2t[u] = bf16r(W2[k * 128 + c]);
  } else {
    int u = t - (128 * 128 + 512 * 128 + 128 * 512);
    if (u < 128){
      float s = 0.f;
      for (int j = 0; j < 128; ++j) s += W_edge[u * 128 + j] * att_edge[j];
      we[u] = s;
    }
  }
}

// K2: LN1 (in fragment layout) + h = xn @ W_lin (bf16 MFMA) -> hq, asrc/adst dots,
//     + grid-stride degree count (cnt zeroed by k_prep0).
__global__ __launch_bounds__(256) void k_hgemm(const float* __restrict__ x,
                                               const unsigned short* __restrict__ Wlt,
                                               const float* __restrict__ ln1_g,
                                               const float* __restrict__ ln1_b,
                                               const float* __restrict__ att_src,
                                               const float* __restrict__ att_dst,
                                               const int* __restrict__ ei,
                                               unsigned short* __restrict__ hq,
                                               float* __restrict__ asrc,
                                               float* __restrict__ adst,
                                               int* __restrict__ cnt, int N, int E){
  int wid = threadIdx.x >> 6, lane = threadIdx.x & 63;
  int rb = blockIdx.x * 64 + wid * 16;
  int row = rb + (lane & 15);
  int rowc = row < N ? row : N - 1;
  int ksub = (lane >> 4) * 8;
  // load x fragment (f32): 32 values of row `rowc` at k = kb*32+ksub+0..7
  float v[4][8];
#pragma unroll
  for (int kb = 0; kb < 4; ++kb){
    float4 p0 = *(const float4*)(x + (size_t)rowc * 128 + kb * 32 + ksub);
    float4 p1 = *(const float4*)(x + (size_t)rowc * 128 + kb * 32 + ksub + 4);
    v[kb][0] = p0.x; v[kb][1] = p0.y; v[kb][2] = p0.z; v[kb][3] = p0.w;
    v[kb][4] = p1.x; v[kb][5] = p1.y; v[kb][6] = p1.z; v[kb][7] = p1.w;
  }
  // LN stats: row's 128 values live on the 4 lanes differing in bits 4,5
  float s = 0.f;
#pragma unroll
  for (int kb = 0; kb < 4; ++kb)
#pragma unroll
    for (int j = 0; j < 8; ++j) s += v[kb][j];
  s += __shfl_xor(s, 16); s += __shfl_xor(s, 32);
  float mu = s * (1.0f / 128.f);
  float q = 0.f;
#pragma unroll
  for (int kb = 0; kb < 4; ++kb)
#pragma unroll
    for (int j = 0; j < 8; ++j){ float d = v[kb][j] - mu; q += d * d; }
  q += __shfl_xor(q, 16); q += __shfl_xor(q, 32);
  float rstd = rsqrtf(q * (1.0f / 128.f) + 1e-5f);
  // gamma/beta + pack bf16 A fragments
  short8 a[4];
#pragma unroll
  for (int kb = 0; kb < 4; ++kb){
    float4 g0 = *(const float4*)(ln1_g + kb * 32 + ksub);
    float4 g1 = *(const float4*)(ln1_g + kb * 32 + ksub + 4);
    float4 b0 = *(const float4*)(ln1_b + kb * 32 + ksub);
    float4 b1 = *(const float4*)(ln1_b + kb * 32 + ksub + 4);
    float gg[8] = {g0.x,g0.y,g0.z,g0.w,g1.x,g1.y,g1.z,g1.w};
    float bb[8] = {b0.x,b0.y,b0.z,b0.w,b1.x,b1.y,b1.z,b1.w};
#pragma unroll
    for (int j = 0; j < 8; ++j)
      a[kb][j] = (short)bf16r((v[kb][j] - mu) * rstd * gg[j] + bb[j]);
  }
  f32x4 acc[8];
#pragma unroll
  for (int ct = 0; ct < 8; ++ct) acc[ct] = (f32x4){0.f, 0.f, 0.f, 0.f};
#pragma unroll
  for (int ct = 0; ct < 8; ++ct){
    int col = ct * 16 + (lane & 15);
#pragma unroll
    for (int kb = 0; kb < 4; ++kb){
      short8 bf = *(const short8*)(Wlt + (size_t)col * 128 + kb * 32 + ksub);
      acc[ct] = __builtin_amdgcn_mfma_f32_16x16x32_bf16(a[kb], bf, acc[ct], 0, 0, 0);
    }
  }
  int r0 = rb + (lane >> 4) * 4;
#pragma unroll
  for (int ct = 0; ct < 8; ++ct){
    int col = ct * 16 + (lane & 15);
#pragma unroll
    for (int j = 0; j < 4; ++j){
      int r = r0 + j;
      if (r < N) hq[(size_t)r * 128 + col] = bf16r(acc[ct][j]);
    }
  }
  float as_v[8], ad_v[8];
#pragma unroll
  for (int ct = 0; ct < 8; ++ct){
    int col = ct * 16 + (lane & 15);
    as_v[ct] = att_src[col];
    ad_v[ct] = att_dst[col];
  }
  float ps[4] = {0.f, 0.f, 0.f, 0.f}, pd[4] = {0.f, 0.f, 0.f, 0.f};
#pragma unroll
  for (int ct = 0; ct < 8; ++ct)
#pragma unroll
    for (int j = 0; j < 4; ++j){
      ps[j] += acc[ct][j] * as_v[ct];
      pd[j] += acc[ct][j] * ad_v[ct];
    }
#pragma unroll
  for (int m = 1; m < 16; m <<= 1)
#pragma unroll
    for (int j = 0; j < 4; ++j){
      ps[j] += __shfl_xor(ps[j], m);
      pd[j] += __shfl_xor(pd[j], m);
    }
  if ((lane & 15) == 0){
#pragma unroll
    for (int j = 0; j < 4; ++j){
      int r = r0 + j;
      if (r < N){ asrc[r] = ps[j]; adst[r] = pd[j]; }
    }
  }
  // degree count (cnt pre-zeroed in k_prep0)
  int t = blockIdx.x * blockDim.x + threadIdx.x;
  int stride = gridDim.x * blockDim.x;
  for (int e = t; e < E; e += stride) atomicAdd(&cnt[ei[E + e]], 1);
}

// K3: exclusive scan (self-sufficient; block recomputes its global offset)
__global__ void k_escan(const int* __restrict__ cnt, int* __restrict__ start,
                        int* __restrict__ cursor, int N){
  int b = blockIdx.x, t = threadIdx.x;
  int base = b * 256;
  int acc = 0;
  for (int i = t; i < base; i += 256) acc += cnt[i];
  acc = wred_sumi(acc);
  __shared__ int wsum[4];
  if ((t & 63) == 0) wsum[t >> 6] = acc;
  __syncthreads();
  int s_off = wsum[0] + wsum[1] + wsum[2] + wsum[3];
  int i = base + t;
  int c = (i < N) ? cnt[i] : 0;
  __shared__ int sd[256];
  sd[t] = c;
  __syncthreads();
  for (int off = 1; off < 256; off <<= 1){
    int vv = (t >= off) ? sd[t - off] : 0;
    __syncthreads();
    sd[t] += vv;
    __syncthreads();
  }
  int st = s_off + sd[t] - c;
  if (i <= N) start[i] = st;
  if (i < N) cursor[i] = st;
}

// K4: fused edge logits + CSR scatter (2 edges per wave), packed (src, alpha)
__global__ void k_edge_scatter(const float* __restrict__ ea, const int* __restrict__ ei,
                               const float* __restrict__ we, const float* __restrict__ asrc,
                               const float* __restrict__ adst, int* __restrict__ cursor,
                               int2* __restrict__ esa, int E){
  int gw = (blockIdx.x * blockDim.x + threadIdx.x) >> 6;
  int lane = threadIdx.x & 63;
  int e = gw * 2 + (lane >> 5);
  int li = lane & 31;
  if (e >= E) return;
  float4 v = *(const float4*)(ea + (size_t)e * 128 + li * 4);
  float4 w = *(const float4*)(we + li * 4);
  float s = v.x * w.x + v.y * w.y + v.z * w.z + v.w * w.w;
#pragma unroll
  for (int m = 16; m; m >>= 1) s += __shfl_xor(s, m);
  if (li == 0){
    int sn = ei[e], dn = ei[E + e];
    float al = asrc[sn] + adst[dn] + s;
    al = al > 0.f ? al : NEG_SLOPE * al;
    int slot = atomicAdd(&cursor[dn], 1);
    esa[slot] = make_int2(sn, __float_as_int(al));
  }
}

// K5: per-node softmax (online, shuffle-broadcast) + weighted gather + residual + LN2
__global__ void k_agg(const float* __restrict__ x, const unsigned short* __restrict__ hq,
                      const int* __restrict__ start, const int2* __restrict__ esa,
                      const float* __restrict__ gat_bias,
                      const float* __restrict__ g2, const float* __restrict__ b2,
                      float* __restrict__ out, unsigned short* __restrict__ xn2q, int N){
  int n = (blockIdx.x * blockDim.x + threadIdx.x) >> 6;
  int lane = threadIdx.x & 63;
  if (n >= N) return;
  int beg = start[n], end = start[n + 1];
  float m = -1e30f, ds = 0.f, a0 = 0.f, a1 = 0.f;
  for (int cb = beg; cb < end; cb += 64){
    int k = end - cb; if (k > 64) k = 64;
    int2 ev = (cb + lane < end) ? esa[cb + lane] : make_int2(0, (int)0xFF800000u);
    float al = __int_as_float(ev.y);
    float mn = fmaxf(m, wred_max(al));
    float sc = __expf(m - mn);
    ds *= sc; a0 *= sc; a1 *= sc;
    m = mn;
    float ex = __expf(al - m);   // invalid lanes: exp(-inf)=0
    int j = 0;
    for (; j + 4 <= k; j += 4){
      float e0 = __shfl(ex, j), e1 = __shfl(ex, j + 1);
      float e2 = __shfl(ex, j + 2), e3 = __shfl(ex, j + 3);
      int s0 = __shfl(ev.x, j), s1 = __shfl(ev.x, j + 1);
      int s2 = __shfl(ev.x, j + 2), s3 = __shfl(ev.x, j + 3);
      unsigned int h0 = *(const unsigned int*)(hq + (size_t)s0 * 128 + lane * 2);
      unsigned int h1 = *(const unsigned int*)(hq + (size_t)s1 * 128 + lane * 2);
      unsigned int h2 = *(const unsigned int*)(hq + (size_t)s2 * 128 + lane * 2);
      unsigned int h3 = *(const unsigned int*)(hq + (size_t)s3 * 128 + lane * 2);
      ds += e0 + e1 + e2 + e3;
      a0 += e0 * bf2f(h0 & 0xffffu) + e1 * bf2f(h1 & 0xffffu)
          + e2 * bf2f(h2 & 0xffffu) + e3 * bf2f(h3 & 0xffffu);
      a1 += e0 * bf2f(h0 >> 16) + e1 * bf2f(h1 >> 16)
          + e2 * bf2f(h2 >> 16) + e3 * bf2f(h3 >> 16);
    }
    for (; j < k; ++j){
      float ej = __shfl(ex, j);
      int sj = __shfl(ev.x, j);
      unsigned int hv = *(const unsigned int*)(hq + (size_t)sj * 128 + lane * 2);
      ds += ej;
      a0 += ej * bf2f(hv & 0xffffu);
      a1 += ej * bf2f(hv >> 16);
    }
  }
  float inv = (end > beg) ? 1.f / fmaxf(ds, 1e-16f) : 0.f;
  a0 *= inv; a1 *= inv;
  float2 xv  = *(const float2*)(x + (size_t)n * 128 + lane * 2);
  float2 gbv = *(const float2*)(gat_bias + lane * 2);
  float r0 = xv.x + a0 + gbv.x;
  float r1 = xv.y + a1 + gbv.y;
  float mu = wred_sum(r0 + r1) * (1.0f / 128.f);
  float d0 = r0 - mu, d1 = r1 - mu;
  float var = wred_sum(d0 * d0 + d1 * d1) * (1.0f / 128.f);
  float rstd = rsqrtf(var + 1e-5f);
  float2 gv = *(const float2*)(g2 + lane * 2);
  float2 bv = *(const float2*)(b2 + lane * 2);
  float o0 = d0 * rstd * gv.x + bv.x;
  float o1 = d1 * rstd * gv.y + bv.y;
  *(float2*)(out + (size_t)n * 128 + lane * 2) = make_float2(r0, r1);
  unsigned int p = (unsigned int)bf16r(o0) | ((unsigned int)bf16r(o1) << 16);
  *(unsigned int*)(xn2q + (size_t)n * 128 + lane * 2) = p;
}

// K6: fused FFN — 512 threads / 8 waves / 64 rows; hidden (64x512 bf16) in swizzled LDS.
__global__ __launch_bounds__(512) void k_ffn(const unsigned short* __restrict__ xn2q,
                                             const unsigned short* __restrict__ W1t,
                                             const unsigned short* __restrict__ W2t,
                                             const float* __restrict__ b1,
                                             const float* __restrict__ b2,
                                             float* __restrict__ out, int N){
  __shared__ unsigned short hid[64 * 512];  // row stride 1024B, XOR-swizzled
  int wid = threadIdx.x >> 6, lane = threadIdx.x & 63;
  int rg = wid >> 1;   // row group 0..3 (16 rows each)
  int ch = wid & 1;    // col half
  int rb = blockIdx.x * 64;
  int lr = rg * 16;
  int arow = rb + lr + (lane & 15);
  int arowc = arow < N ? arow : N - 1;
  int ksub = (lane >> 4) * 8;
  short8 a[4];
#pragma unroll
  for (int kb = 0; kb < 4; ++kb)
    a[kb] = *(const short8*)(xn2q + (size_t)arowc * 128 + kb * 32 + ksub);
  int lr0 = lr + (lane >> 4) * 4;
#pragma unroll 4
  for (int ct = 0; ct < 16; ++ct){
    int col = ch * 256 + ct * 16 + (lane & 15);
    f32x4 acc = {0.f, 0.f, 0.f, 0.f};
#pragma unroll
    for (int kb = 0; kb < 4; ++kb){
      short8 bf = *(const short8*)(W1t + (size_t)col * 128 + kb * 32 + ksub);
      acc = __builtin_amdgcn_mfma_f32_16x16x32_bf16(a[kb], bf, acc, 0, 0, 0);
    }
    float bias = b1[col];
#pragma unroll
    for (int j = 0; j < 4; ++j){
      float v = acc[j] + bias;
      v = v > 0.f ? v : 0.f;
      int row = lr0 + j;
      int byte = (col * 2) ^ ((row & 7) << 4);
      *(unsigned short*)((char*)hid + row * 1024 + byte) = bf16r(v);
    }
  }
  __syncthreads();
  f32x4 acc2[4];
#pragma unroll
  for (int ct = 0; ct < 4; ++ct) acc2[ct] = (f32x4){0.f, 0.f, 0.f, 0.f};
  int arow2 = lr + (lane & 15);
#pragma unroll 2
  for (int kb = 0; kb < 16; ++kb){
    int kbyte = (kb * 32 + ksub) * 2;
    int sb = kbyte ^ ((arow2 & 7) << 4);
    short8 af = *(const short8*)((const char*)hid + arow2 * 1024 + sb);
#pragma unroll
    for (int ct = 0; ct < 4; ++ct){
      int col = ch * 64 + ct * 16 + (lane & 15);
      short8 bf = *(const short8*)(W2t + (size_t)col * 512 + kb * 32 + ksub);
      acc2[ct] = __builtin_amdgcn_mfma_f32_16x16x32_bf16(af, bf, acc2[ct], 0, 0, 0);
    }
  }
  int r0 = rb + lr0;
#pragma unroll
  for (int ct = 0; ct < 4; ++ct){
    int col = ch * 64 + ct * 16 + (lane & 15);
    float bias = b2[col];
#pragma unroll
    for (int j = 0; j < 4; ++j){
      int row = r0 + j;
      if (row < N) out[(size_t)row * 128 + col] += acc2[ct][j] + bias;
    }
  }
}

extern "C" void kernel_launch(void* const* d_in, const int* in_sizes, int n_in,
                              void* d_out, int out_size, void* d_ws, size_t ws_size,
                              hipStream_t stream){
  const float* x        = (const float*)d_in[0];
  const int*   ei       = (const int*)  d_in[1];
  const float* ea       = (const float*)d_in[2];
  const float* ln1_g    = (const float*)d_in[3];
  const float* ln1_b    = (const float*)d_in[4];
  const float* W_lin    = (const float*)d_in[5];
  const float* att_src  = (const float*)d_in[6];
  const float* att_dst  = (const float*)d_in[7];
  const float* W_edge   = (const float*)d_in[8];
  const float* att_edge = (const float*)d_in[9];
  const float* gat_bias = (const float*)d_in[10];
  const float* ln2_g    = (const float*)d_in[11];
  const float* ln2_b    = (const float*)d_in[12];
  const float* W1       = (const float*)d_in[13];
  const float* b1       = (const float*)d_in[14];
  const float* W2       = (const float*)d_in[15];
  const float* b2       = (const float*)d_in[16];

  const int N = in_sizes[0] / 128;
  const int E = in_sizes[2] / 128;
  float* out = (float*)d_out;

  char* p = (char*)d_ws;
  auto carve = [&](size_t bytes) -> char* {
    char* r = p; p += (bytes + 255) & ~(size_t)255; return r;
  };
  unsigned short* hq       = (unsigned short*)carve((size_t)N * 128 * 2);
  unsigned short* xn2q     = (unsigned short*)carve((size_t)N * 128 * 2);
  float*          asrc     = (float*)carve((size_t)N * 4);
  float*          adst     = (float*)carve((size_t)N * 4);
  int2*           esa      = (int2*)carve((size_t)E * 8);
  int*            cnt      = (int*)carve((size_t)N * 4);
  int*            cursor   = (int*)carve((size_t)N * 4);
  int*            start    = (int*)carve((size_t)(N + 1) * 4);
  unsigned short* Wlt      = (unsigned short*)carve(128 * 128 * 2);
  unsigned short* W1t      = (unsigned short*)carve(512 * 128 * 2);
  unsigned short* W2t      = (unsigned short*)carve(128 * 512 * 2);
  float*          we       = (float*)carve(128 * 4);

  k_prep0<<<(128*128 + 512*128 + 128*512 + 128 + 255) / 256, 256, 0, stream>>>(
      W_lin, W1, W2, W_edge, att_edge, Wlt, W1t, W2t, we, cnt, N);
  k_hgemm<<<(N + 63) / 64, 256, 0, stream>>>(x, Wlt, ln1_g, ln1_b, att_src, att_dst, ei,
                                             hq, asrc, adst, cnt, N, E);
  k_escan<<<N / 256 + 1, 256, 0, stream>>>(cnt, start, cursor, N);
  k_edge_scatter<<<(E + 7) / 8, 256, 0, stream>>>(ea, ei, we, asrc, adst, cursor, esa, E);
  k_agg<<<(N + 3) / 4, 256, 0, stream>>>(x, hq, start, esa, gat_bias, ln2_g, ln2_b,
                                         out, xn2q, N);
  k_ffn<<<(N + 63) / 64, 512, 0, stream>>>(xn2q, W1t, W2t, b1, b2, out, N);
}